// Round 10
// baseline (2688.405 us; speedup 1.0000x reference)
//
#include <hip/hip_runtime.h>
#include <cstddef>
#include <cstdint>

constexpr int NN = 50000;          // nodes
constexpr int NE = 800000;         // edges (no self loops)
constexpr int ET = NE + NN;        // edges + self loops
constexpr int NB = 50;             // graphs
constexpr int SCAN_B = 1024;
constexpr int NBLK = (NN + SCAN_B - 1) / SCAN_B;   // 49

__device__ __forceinline__ float eluf(float x) { return x > 0.f ? x : expm1f(x); }

// round-to-nearest-even fp32 -> bf16 (as ushort)
__device__ __forceinline__ unsigned short f2bf(float f) {
    unsigned int u = __float_as_uint(f);
    unsigned int r = (u + 0x7fffu + ((u >> 16) & 1u)) >> 16;
    return (unsigned short)r;
}

// ---------------- kernel: edge encoder MLP + sum(ew) + dst histogram ----------------
__global__ void edge_mlp_kernel(const float* __restrict__ ea,
                                const float* __restrict__ w1, const float* __restrict__ b1,
                                const float* __restrict__ w2, const float* __restrict__ b2,
                                const int* __restrict__ ei_dst, int* __restrict__ deg,
                                float* __restrict__ ew, float* __restrict__ ew_sum) {
    // weights transposed+interleaved: wt[j*8 + {0..4}]=w1[i][j], [5]=b1[j], [6]=w2[j]
    __shared__ float wt[64 * 8];
    int t = threadIdx.x;
    if (t < 64) {
        #pragma unroll
        for (int i = 0; i < 5; ++i) wt[t * 8 + i] = w1[i * 64 + t];
        wt[t * 8 + 5] = b1[t];
        wt[t * 8 + 6] = w2[t];
        wt[t * 8 + 7] = 0.f;
    }
    __syncthreads();
    int e = blockIdx.x * 256 + t;
    float val = 0.f;
    if (e < NE) {
        float a0 = ea[e*5+0], a1 = ea[e*5+1], a2 = ea[e*5+2], a3 = ea[e*5+3], a4 = ea[e*5+4];
        float acc = b2[0];
        #pragma unroll 8
        for (int j = 0; j < 64; ++j) {
            const float4 lo = *(const float4*)&wt[j * 8];
            const float4 hi = *(const float4*)&wt[j * 8 + 4];
            float hj = hi.y + a0*lo.x + a1*lo.y + a2*lo.z + a3*lo.w + a4*hi.x;
            acc += fmaxf(hj, 0.f) * hi.z;
        }
        val = 1.f / (1.f + __expf(-acc));
        ew[e] = val;
    }
    if (e < ET) {
        int d = (e < NE) ? ei_dst[e] : (e - NE);
        atomicAdd(&deg[d], 1);
    }
    __shared__ float red[256];
    red[t] = val;
    __syncthreads();
    for (int off = 128; off > 0; off >>= 1) {
        if (t < off) red[t] += red[t + off];
        __syncthreads();
    }
    if (t == 0) atomicAdd(ew_sum, red[0]);
}

// ---------------- scan phase A (+ fused prep: self-loop ew fill, ce[l][h]) ----------------
__global__ void scan_blocks(const int* __restrict__ deg, int* __restrict__ row_ptr,
                            int* __restrict__ bsum,
                            const float* __restrict__ We, const float* __restrict__ att_e,
                            const float* __restrict__ ew_sum, float* __restrict__ ew,
                            float* __restrict__ ce) {
    __shared__ int sdata[SCAN_B];
    int t = threadIdx.x;
    int i = blockIdx.x * SCAN_B + t;
    // fused prep work (independent of the scan)
    if (i < NN) ew[NE + i] = ew_sum[0] * (1.f / (float)NE);
    if (i < 12) {
        int l = i >> 2, h = i & 3;
        float s = 0.f;
        for (int c = 0; c < 64; ++c)
            s += We[l*256 + h*64 + c] * att_e[l*256 + h*64 + c];
        ce[i] = s;
    }
    int v = (i < NN) ? deg[i] : 0;
    sdata[t] = v;
    __syncthreads();
    for (int off = 1; off < SCAN_B; off <<= 1) {
        int tv = (t >= off) ? sdata[t - off] : 0;
        __syncthreads();
        sdata[t] += tv;
        __syncthreads();
    }
    if (i < NN) row_ptr[i + 1] = sdata[t];
    if (t == SCAN_B - 1) bsum[blockIdx.x] = sdata[t];
}

// scan phase B+C fused: each block wave-scans the 49 block sums in-LDS, then
// adds the offset to its range of row_ptr. (Replaces scan_bsum + scan_add.)
__global__ void scan_fixup(const int* __restrict__ bsum, int* __restrict__ row_ptr) {
    __shared__ int sboff[64];
    int t = threadIdx.x;   // 256
    if (t < 64) {
        int v = (t < NBLK) ? bsum[t] : 0;
        int inc = v;
        #pragma unroll
        for (int off = 1; off < 64; off <<= 1) {
            int n = __shfl_up(inc, off);
            if (t >= off) inc += n;
        }
        sboff[t] = inc - v;   // exclusive scan
    }
    __syncthreads();
    int i = blockIdx.x * 256 + t;
    if (i < NN) row_ptr[i + 1] += sboff[i >> 10];
    if (i == 0) row_ptr[0] = 0;
}

// write per-slot {src, ew} as one int2 so the aggregate does a single 8-B load
__global__ void scatter_kernel(const int* __restrict__ ei_src, const int* __restrict__ ei_dst,
                               const int* __restrict__ row_ptr, const float* __restrict__ ew,
                               int* __restrict__ fill, int2* __restrict__ csr) {
    int e = blockIdx.x * 256 + threadIdx.x;
    if (e >= ET) return;
    int d = (e < NE) ? ei_dst[e] : (e - NE);
    int s = (e < NE) ? ei_src[e] : (e - NE);
    int pos = atomicAdd(&fill[d], 1);
    csr[row_ptr[d] + pos] = make_int2(s, __float_as_int(ew[e]));
}

// ---------------- kernel: h = xin @ W (bf16 via LDS bounce), fused alphas ----------------
// R7 body with float2 LDS reads (half the ds_read issues). __launch_bounds__(256,4)
// caps VGPR at 128 — guards against the R8 64-cap spill cliff.
template <int FIN>
__global__ __launch_bounds__(256, 4)
void node_transform(const float* __restrict__ xin, const float* __restrict__ W,
                    const float* __restrict__ a_s, const float* __restrict__ a_d,
                    unsigned short* __restrict__ hb, float* __restrict__ asrc,
                    float* __restrict__ adst) {
    const int t = threadIdx.x;
    const int n0 = blockIdx.x * 8;
    __shared__ float xr[8 * FIN];
    __shared__ unsigned short hs[8 * 256];   // 4 KB staging for wide stores
    for (int i = t; i < 8 * FIN; i += 256) {
        int node = n0 + i / FIN;
        xr[i] = (node < NN) ? xin[(size_t)node * FIN + (i % FIN)] : 0.f;
    }
    __syncthreads();
    float acc[8];
    #pragma unroll
    for (int i = 0; i < 8; ++i) acc[i] = 0.f;
    for (int k = 0; k < FIN; k += 2) {
        float w0 = W[k * 256 + t];
        float w1 = W[(k + 1) * 256 + t];
        #pragma unroll
        for (int i = 0; i < 8; ++i) {
            const float2 xv = *(const float2*)&xr[i * FIN + k];
            acc[i] += xv.x * w0 + xv.y * w1;
        }
    }
    float as_t = a_s[t], ad_t = a_d[t];
    int lane = t & 63, head = t >> 6;
    #pragma unroll
    for (int i = 0; i < 8; ++i) {
        hs[i * 256 + t] = f2bf(acc[i]);
        float vs = acc[i] * as_t, vd = acc[i] * ad_t;
        #pragma unroll
        for (int mask = 1; mask <= 32; mask <<= 1) {
            vs += __shfl_xor(vs, mask);
            vd += __shfl_xor(vd, mask);
        }
        if (lane == 0 && n0 + i < NN) {
            asrc[(n0 + i) * 4 + head] = vs;
            adst[(n0 + i) * 4 + head] = vd;
        }
    }
    __syncthreads();
    // 256 threads x 16 B = 4096 B = the block's 8 rows of 512 B, fully coalesced
    if (n0 + (t >> 5) < NN)
        ((uint4*)(hb + (size_t)n0 * 256))[t] = ((const uint4*)hs)[t];
}

// ---------------- kernel: per-dst-node softmax-free aggregation ----------------
// One wave per node; lane half hf processes edges start+hf, start+hf+2, ...
// 4-deep gather pipeline per half (4 uint4 gathers in flight).
__global__ __launch_bounds__(256, 4)
void gat_aggregate(const unsigned short* __restrict__ hb,
                   const float* __restrict__ asrc, const float* __restrict__ adst,
                   const int2* __restrict__ csr, const float* __restrict__ ce_l,
                   const float* __restrict__ bias_l,
                   const int* __restrict__ row_ptr,
                   float* __restrict__ xi, int residual) {
    int widx = (blockIdx.x * 256 + threadIdx.x) >> 6;   // node
    if (widx >= NN) return;
    int lane = threadIdx.x & 63;
    int half = lane >> 5;
    int li = lane & 31;        // channels li*8 .. li*8+7
    int head = li >> 3;        // head
    int start = row_ptr[widx], end = row_ptr[widx + 1];
    float adw = adst[widx * 4 + head];
    float ceh = ce_l[head];
    const uint4* hbv = (const uint4*)hb;

    float acc[8];
    #pragma unroll
    for (int r = 0; r < 8; ++r) acc[r] = 0.f;
    float psum = 0.f;

    #define PROC(EI)                                                                  \
        {                                                                             \
            const int2 se = csr[EI];                                                  \
            int s = se.x;                                                             \
            float w = __int_as_float(se.y);                                           \
            const uint4 q = hbv[(unsigned)s * 32u + (unsigned)li];                    \
            float v = asrc[s * 4 + head] + adw + w * ceh;                             \
            v = v > 0.f ? v : 0.2f * v;                                               \
            float p = __expf(v);                                                      \
            psum += p;                                                                \
            acc[0] += p * __uint_as_float(q.x << 16);                                 \
            acc[1] += p * __uint_as_float(q.x & 0xffff0000u);                         \
            acc[2] += p * __uint_as_float(q.y << 16);                                 \
            acc[3] += p * __uint_as_float(q.y & 0xffff0000u);                         \
            acc[4] += p * __uint_as_float(q.z << 16);                                 \
            acc[5] += p * __uint_as_float(q.z & 0xffff0000u);                         \
            acc[6] += p * __uint_as_float(q.w << 16);                                 \
            acc[7] += p * __uint_as_float(q.w & 0xffff0000u);                         \
        }

    int ei = start + half;
    for (; ei + 6 < end; ei += 8) {   // 4 edges per half per iter -> 4 gathers in flight
        PROC(ei);
        PROC(ei + 2);
        PROC(ei + 4);
        PROC(ei + 6);
    }
    for (; ei < end; ei += 2) PROC(ei);
    #undef PROC

    // combine the two halves (same channels, disjoint edge sets)
    psum += __shfl_xor(psum, 32);
    #pragma unroll
    for (int r = 0; r < 8; ++r) acc[r] += __shfl_xor(acc[r], 32);

    float inv = 1.f / (psum + 1e-16f);
    #pragma unroll
    for (int r = 0; r < 8; ++r) acc[r] *= inv;

    // head mean: lanes li, li^8, li^16, li^24 hold same channel-in-head, different heads
    #pragma unroll
    for (int r = 0; r < 8; ++r) {
        acc[r] += __shfl_xor(acc[r], 8);
        acc[r] += __shfl_xor(acc[r], 16);
        acc[r] *= 0.25f;
    }

    if (lane < 8) {
        int c0 = lane * 8;
        const float4 b0 = *(const float4*)(bias_l + c0);
        const float4 b1 = *(const float4*)(bias_l + c0 + 4);
        float4 v0, v1;
        v0.x = acc[0] + b0.x; v0.y = acc[1] + b0.y; v0.z = acc[2] + b0.z; v0.w = acc[3] + b0.w;
        v1.x = acc[4] + b1.x; v1.y = acc[5] + b1.y; v1.z = acc[6] + b1.z; v1.w = acc[7] + b1.w;
        float* xo = xi + (size_t)widx * 64 + c0;
        if (residual) {
            const float4 p0 = *(const float4*)xo;
            const float4 p1 = *(const float4*)(xo + 4);
            v0.x += p0.x; v0.y += p0.y; v0.z += p0.z; v0.w += p0.w;
            v1.x += p1.x; v1.y += p1.y; v1.z += p1.z; v1.w += p1.w;
        }
        v0.x = eluf(v0.x); v0.y = eluf(v0.y); v0.z = eluf(v0.z); v0.w = eluf(v0.w);
        v1.x = eluf(v1.x); v1.y = eluf(v1.y); v1.z = eluf(v1.z); v1.w = eluf(v1.w);
        *(float4*)xo = v0;
        *(float4*)(xo + 4) = v1;
    }
}

// ---------------- kernel: LN + 2-layer MLP on the 50 target nodes ----------------
__global__ void readout_kernel(const float* __restrict__ xi, const int* __restrict__ batch,
                               const float* __restrict__ ln_g, const float* __restrict__ ln_b,
                               const float* __restrict__ l1w, const float* __restrict__ l1b,
                               const float* __restrict__ l2w, const float* __restrict__ l2b,
                               float* __restrict__ out) {
    int b = blockIdx.x;
    int t = threadIdx.x;   // 64 threads, one wave
    __shared__ int tg_s;
    if (t == 0) {
        int lo = 0, hi = NN;
        while (lo < hi) {
            int mid = (lo + hi) >> 1;
            if (batch[mid] < b) lo = mid + 1; else hi = mid;
        }
        tg_s = lo;
    }
    __syncthreads();
    int tg = tg_s;
    float x = xi[(size_t)tg * 64 + t];
    float s = x;
    #pragma unroll
    for (int mask = 1; mask <= 32; mask <<= 1) s += __shfl_xor(s, mask);
    float mu = s * (1.f / 64.f);
    float d = x - mu;
    float v = d * d;
    #pragma unroll
    for (int mask = 1; mask <= 32; mask <<= 1) v += __shfl_xor(v, mask);
    float var = v * (1.f / 64.f);
    float xn = d * rsqrtf(var + 1e-5f) * ln_g[t] + ln_b[t];
    __shared__ float sx[64];
    sx[t] = xn;
    __syncthreads();
    float acc = l1b[t];
    for (int k = 0; k < 64; ++k) acc += sx[k] * l1w[k * 64 + t];
    acc = eluf(acc);
    __shared__ float st[64];
    st[t] = acc;
    __syncthreads();
    if (t < 3) {
        float o = l2b[t];
        for (int k = 0; k < 64; ++k) o += st[k] * l2w[k * 3 + t];
        out[b * 3 + t] = o;
    }
}

extern "C" void kernel_launch(void* const* d_in, const int* in_sizes, int n_in,
                              void* d_out, int out_size, void* d_ws, size_t ws_size,
                              hipStream_t stream) {
    const float* x        = (const float*)d_in[0];
    const int*   ei       = (const int*)d_in[1];
    const float* ea       = (const float*)d_in[2];
    const int*   batch    = (const int*)d_in[3];
    const float* ee_w1    = (const float*)d_in[4];
    const float* ee_b1    = (const float*)d_in[5];
    const float* ee_w2    = (const float*)d_in[6];
    const float* ee_b2    = (const float*)d_in[7];
    const float* W1       = (const float*)d_in[8];
    const float* Ws       = (const float*)d_in[9];
    const float* att_src  = (const float*)d_in[10];
    const float* att_dst  = (const float*)d_in[11];
    const float* We       = (const float*)d_in[12];
    const float* att_e    = (const float*)d_in[13];
    const float* bias     = (const float*)d_in[14];
    const float* ln_g     = (const float*)d_in[15];
    const float* ln_b     = (const float*)d_in[16];
    const float* lin1_w   = (const float*)d_in[17];
    const float* lin1_b   = (const float*)d_in[18];
    const float* lin2_w   = (const float*)d_in[19];
    const float* lin2_b   = (const float*)d_in[20];
    float* out = (float*)d_out;

    // ---- workspace carve-up (256B aligned) ----
    char* ws = (char*)d_ws;
    size_t off = 0;
    auto alloc = [&](size_t bytes) -> char* {
        char* p = ws + off;
        off += (bytes + 255) & ~(size_t)255;
        return p;
    };
    float* ew      = (float*)alloc((size_t)ET * 4);
    float* ce      = (float*)alloc(12 * 4);
    unsigned short* hbuf = (unsigned short*)alloc((size_t)NN * 256 * 2);
    float* asrc    = (float*)alloc((size_t)NN * 4 * 4);
    float* adst    = (float*)alloc((size_t)NN * 4 * 4);
    float* xi      = (float*)alloc((size_t)NN * 64 * 4);
    int*   deg     = (int*)alloc(((size_t)NN * 2 + 64) * 4); // deg | fill | ew_sum
    int*   fill    = deg + NN;
    float* ew_sum  = (float*)(deg + 2 * NN);
    int*   row_ptr = (int*)alloc((size_t)(NN + 1) * 4);
    int*   bsum    = (int*)alloc(64 * 4);
    int2*  csr     = (int2*)alloc((size_t)ET * 8);
    (void)ws_size; (void)n_in; (void)in_sizes; (void)out_size;

    const int* ei_src = ei;
    const int* ei_dst = ei + NE;

    // 1. edge encoder + dst histogram (fused); single memset covers deg+fill+ew_sum
    hipMemsetAsync(deg, 0, ((size_t)NN * 2 + 64) * 4, stream);
    edge_mlp_kernel<<<(ET + 255) / 256, 256, 0, stream>>>(ea, ee_w1, ee_b1, ee_w2, ee_b2,
                                                          ei_dst, deg, ew, ew_sum);

    // 2. CSR by dst (multi-block scan; phase A also does self-loop ew fill + ce)
    scan_blocks<<<NBLK, SCAN_B, 0, stream>>>(deg, row_ptr, bsum, We, att_e, ew_sum, ew, ce);
    scan_fixup<<<(NN + 255) / 256, 256, 0, stream>>>(bsum, row_ptr);
    scatter_kernel<<<(ET + 255) / 256, 256, 0, stream>>>(ei_src, ei_dst, row_ptr, ew, fill, csr);

    // 3. three GAT layers
    const int ntBlocks = (NN + 7) / 8;
    const int agBlocks = (NN + 3) / 4;
    // layer 0
    node_transform<16><<<ntBlocks, 256, 0, stream>>>(x, W1, att_src + 0 * 256, att_dst + 0 * 256,
                                                     hbuf, asrc, adst);
    gat_aggregate<<<agBlocks, 256, 0, stream>>>(hbuf, asrc, adst, csr, ce + 0 * 4,
                                                bias + 0 * 64, row_ptr, xi, 0);
    // layers 1..2 (residual)
    for (int l = 0; l < 2; ++l) {
        node_transform<64><<<ntBlocks, 256, 0, stream>>>(xi, Ws + (size_t)l * 64 * 256,
                                                         att_src + (l + 1) * 256,
                                                         att_dst + (l + 1) * 256,
                                                         hbuf, asrc, adst);
        gat_aggregate<<<agBlocks, 256, 0, stream>>>(hbuf, asrc, adst, csr, ce + (l + 1) * 4,
                                                    bias + (l + 1) * 64, row_ptr, xi, 1);
    }

    // 4. readout
    readout_kernel<<<NB, 64, 0, stream>>>(xi, batch, ln_g, ln_b, lin1_w, lin1_b, lin2_w, lin2_b, out);
}

// Round 11
// 598.501 us; speedup vs baseline: 4.4919x; 4.4919x over previous
//
#include <hip/hip_runtime.h>
#include <cstddef>
#include <cstdint>

constexpr int NN = 50000;          // nodes
constexpr int NE = 800000;         // edges (no self loops)
constexpr int ET = NE + NN;        // edges + self loops
constexpr int NB = 50;             // graphs
constexpr int SCAN_B = 1024;
constexpr int NBLK = (NN + SCAN_B - 1) / SCAN_B;   // 49

__device__ __forceinline__ float eluf(float x) { return x > 0.f ? x : expm1f(x); }

// round-to-nearest-even fp32 -> bf16 (as ushort)
__device__ __forceinline__ unsigned short f2bf(float f) {
    unsigned int u = __float_as_uint(f);
    unsigned int r = (u + 0x7fffu + ((u >> 16) & 1u)) >> 16;
    return (unsigned short)r;
}

// ---------------- kernel: edge encoder MLP + sum(ew) + dst histogram ----------------
__global__ void edge_mlp_kernel(const float* __restrict__ ea,
                                const float* __restrict__ w1, const float* __restrict__ b1,
                                const float* __restrict__ w2, const float* __restrict__ b2,
                                const int* __restrict__ ei_dst, int* __restrict__ deg,
                                float* __restrict__ ew, float* __restrict__ ew_sum) {
    // weights transposed+interleaved: wt[j*8 + {0..4}]=w1[i][j], [5]=b1[j], [6]=w2[j]
    __shared__ float wt[64 * 8];
    int t = threadIdx.x;
    if (t < 64) {
        #pragma unroll
        for (int i = 0; i < 5; ++i) wt[t * 8 + i] = w1[i * 64 + t];
        wt[t * 8 + 5] = b1[t];
        wt[t * 8 + 6] = w2[t];
        wt[t * 8 + 7] = 0.f;
    }
    __syncthreads();
    int e = blockIdx.x * 256 + t;
    float val = 0.f;
    if (e < NE) {
        float a0 = ea[e*5+0], a1 = ea[e*5+1], a2 = ea[e*5+2], a3 = ea[e*5+3], a4 = ea[e*5+4];
        float acc = b2[0];
        #pragma unroll 8
        for (int j = 0; j < 64; ++j) {
            const float4 lo = *(const float4*)&wt[j * 8];
            const float4 hi = *(const float4*)&wt[j * 8 + 4];
            float hj = hi.y + a0*lo.x + a1*lo.y + a2*lo.z + a3*lo.w + a4*hi.x;
            acc += fmaxf(hj, 0.f) * hi.z;
        }
        val = 1.f / (1.f + __expf(-acc));
        ew[e] = val;
    }
    if (e < ET) {
        int d = (e < NE) ? ei_dst[e] : (e - NE);
        atomicAdd(&deg[d], 1);
    }
    __shared__ float red[256];
    red[t] = val;
    __syncthreads();
    for (int off = 128; off > 0; off >>= 1) {
        if (t < off) red[t] += red[t + off];
        __syncthreads();
    }
    if (t == 0) atomicAdd(ew_sum, red[0]);
}

// ---------------- scan phase A (+ fused prep: self-loop ew fill, ce[l][h]) ----------------
__global__ void scan_blocks(const int* __restrict__ deg, int* __restrict__ row_ptr,
                            int* __restrict__ bsum,
                            const float* __restrict__ We, const float* __restrict__ att_e,
                            const float* __restrict__ ew_sum, float* __restrict__ ew,
                            float* __restrict__ ce) {
    __shared__ int sdata[SCAN_B];
    int t = threadIdx.x;
    int i = blockIdx.x * SCAN_B + t;
    // fused prep work (independent of the scan)
    if (i < NN) ew[NE + i] = ew_sum[0] * (1.f / (float)NE);
    if (i < 12) {
        int l = i >> 2, h = i & 3;
        float s = 0.f;
        for (int c = 0; c < 64; ++c)
            s += We[l*256 + h*64 + c] * att_e[l*256 + h*64 + c];
        ce[i] = s;
    }
    int v = (i < NN) ? deg[i] : 0;
    sdata[t] = v;
    __syncthreads();
    for (int off = 1; off < SCAN_B; off <<= 1) {
        int tv = (t >= off) ? sdata[t - off] : 0;
        __syncthreads();
        sdata[t] += tv;
        __syncthreads();
    }
    if (i < NN) row_ptr[i + 1] = sdata[t];
    if (t == SCAN_B - 1) bsum[blockIdx.x] = sdata[t];
}

// scan phase B+C fused: each block wave-scans the 49 block sums in-LDS, then
// adds the offset to its range of row_ptr.
__global__ void scan_fixup(const int* __restrict__ bsum, int* __restrict__ row_ptr) {
    __shared__ int sboff[64];
    int t = threadIdx.x;   // 256
    if (t < 64) {
        int v = (t < NBLK) ? bsum[t] : 0;
        int inc = v;
        #pragma unroll
        for (int off = 1; off < 64; off <<= 1) {
            int n = __shfl_up(inc, off);
            if (t >= off) inc += n;
        }
        sboff[t] = inc - v;   // exclusive scan
    }
    __syncthreads();
    int i = blockIdx.x * 256 + t;
    if (i < NN) row_ptr[i + 1] += sboff[i >> 10];
    if (i == 0) row_ptr[0] = 0;
}

// write per-slot {src, ew} as one int2 so the aggregate does a single 8-B load
__global__ void scatter_kernel(const int* __restrict__ ei_src, const int* __restrict__ ei_dst,
                               const int* __restrict__ row_ptr, const float* __restrict__ ew,
                               int* __restrict__ fill, int2* __restrict__ csr) {
    int e = blockIdx.x * 256 + threadIdx.x;
    if (e >= ET) return;
    int d = (e < NE) ? ei_dst[e] : (e - NE);
    int s = (e < NE) ? ei_src[e] : (e - NE);
    int pos = atomicAdd(&fill[d], 1);
    csr[row_ptr[d] + pos] = make_int2(s, __float_as_int(ew[e]));
}

// ---------------- kernel: h = xin @ W (bf16 via LDS bounce), fused alphas ----------------
// EXACT R9 body: scalar LDS reads + coalesced 16-B store bounce. Vectorized LDS
// reads (float2/float4) in this kernel trigger catastrophic scratch spill (R8, R10).
template <int FIN>
__global__ void node_transform(const float* __restrict__ xin, const float* __restrict__ W,
                               const float* __restrict__ a_s, const float* __restrict__ a_d,
                               unsigned short* __restrict__ hb, float* __restrict__ asrc,
                               float* __restrict__ adst) {
    const int t = threadIdx.x;
    const int n0 = blockIdx.x * 8;
    __shared__ float xr[8 * FIN];
    __shared__ unsigned short hs[8 * 256];   // 4 KB staging for wide stores
    for (int i = t; i < 8 * FIN; i += 256) {
        int node = n0 + i / FIN;
        xr[i] = (node < NN) ? xin[(size_t)node * FIN + (i % FIN)] : 0.f;
    }
    __syncthreads();
    float acc[8];
    #pragma unroll
    for (int i = 0; i < 8; ++i) acc[i] = 0.f;
    for (int k = 0; k < FIN; ++k) {
        float wv = W[k * 256 + t];
        #pragma unroll
        for (int i = 0; i < 8; ++i) acc[i] += xr[i * FIN + k] * wv;
    }
    float as_t = a_s[t], ad_t = a_d[t];
    int lane = t & 63, head = t >> 6;
    #pragma unroll
    for (int i = 0; i < 8; ++i) {
        hs[i * 256 + t] = f2bf(acc[i]);
        float vs = acc[i] * as_t, vd = acc[i] * ad_t;
        #pragma unroll
        for (int mask = 1; mask <= 32; mask <<= 1) {
            vs += __shfl_xor(vs, mask);
            vd += __shfl_xor(vd, mask);
        }
        if (lane == 0 && n0 + i < NN) {
            asrc[(n0 + i) * 4 + head] = vs;
            adst[(n0 + i) * 4 + head] = vd;
        }
    }
    __syncthreads();
    // 256 threads x 16 B = 4096 B = the block's 8 rows of 512 B, fully coalesced
    if (n0 + (t >> 5) < NN)
        ((uint4*)(hb + (size_t)n0 * 256))[t] = ((const uint4*)hs)[t];
}

// ---------------- kernel: per-dst-node softmax-free aggregation ----------------
// One wave per node; lane half hf processes edges start+hf, start+hf+2, ...
// 4-deep gather pipeline per half (4 uint4 gathers in flight).
__global__ __launch_bounds__(256, 4)
void gat_aggregate(const unsigned short* __restrict__ hb,
                   const float* __restrict__ asrc, const float* __restrict__ adst,
                   const int2* __restrict__ csr, const float* __restrict__ ce_l,
                   const float* __restrict__ bias_l,
                   const int* __restrict__ row_ptr,
                   float* __restrict__ xi, int residual) {
    int widx = (blockIdx.x * 256 + threadIdx.x) >> 6;   // node
    if (widx >= NN) return;
    int lane = threadIdx.x & 63;
    int half = lane >> 5;
    int li = lane & 31;        // channels li*8 .. li*8+7
    int head = li >> 3;        // head
    int start = row_ptr[widx], end = row_ptr[widx + 1];
    float adw = adst[widx * 4 + head];
    float ceh = ce_l[head];
    const uint4* hbv = (const uint4*)hb;

    float acc[8];
    #pragma unroll
    for (int r = 0; r < 8; ++r) acc[r] = 0.f;
    float psum = 0.f;

    #define PROC(EI)                                                                  \
        {                                                                             \
            const int2 se = csr[EI];                                                  \
            int s = se.x;                                                             \
            float w = __int_as_float(se.y);                                           \
            const uint4 q = hbv[(unsigned)s * 32u + (unsigned)li];                    \
            float v = asrc[s * 4 + head] + adw + w * ceh;                             \
            v = v > 0.f ? v : 0.2f * v;                                               \
            float p = __expf(v);                                                      \
            psum += p;                                                                \
            acc[0] += p * __uint_as_float(q.x << 16);                                 \
            acc[1] += p * __uint_as_float(q.x & 0xffff0000u);                         \
            acc[2] += p * __uint_as_float(q.y << 16);                                 \
            acc[3] += p * __uint_as_float(q.y & 0xffff0000u);                         \
            acc[4] += p * __uint_as_float(q.z << 16);                                 \
            acc[5] += p * __uint_as_float(q.z & 0xffff0000u);                         \
            acc[6] += p * __uint_as_float(q.w << 16);                                 \
            acc[7] += p * __uint_as_float(q.w & 0xffff0000u);                         \
        }

    int ei = start + half;
    for (; ei + 6 < end; ei += 8) {   // 4 edges per half per iter -> 4 gathers in flight
        PROC(ei);
        PROC(ei + 2);
        PROC(ei + 4);
        PROC(ei + 6);
    }
    for (; ei < end; ei += 2) PROC(ei);
    #undef PROC

    // combine the two halves (same channels, disjoint edge sets)
    psum += __shfl_xor(psum, 32);
    #pragma unroll
    for (int r = 0; r < 8; ++r) acc[r] += __shfl_xor(acc[r], 32);

    float inv = 1.f / (psum + 1e-16f);
    #pragma unroll
    for (int r = 0; r < 8; ++r) acc[r] *= inv;

    // head mean: lanes li, li^8, li^16, li^24 hold same channel-in-head, different heads
    #pragma unroll
    for (int r = 0; r < 8; ++r) {
        acc[r] += __shfl_xor(acc[r], 8);
        acc[r] += __shfl_xor(acc[r], 16);
        acc[r] *= 0.25f;
    }

    if (lane < 8) {
        int c0 = lane * 8;
        const float4 b0 = *(const float4*)(bias_l + c0);
        const float4 b1 = *(const float4*)(bias_l + c0 + 4);
        float4 v0, v1;
        v0.x = acc[0] + b0.x; v0.y = acc[1] + b0.y; v0.z = acc[2] + b0.z; v0.w = acc[3] + b0.w;
        v1.x = acc[4] + b1.x; v1.y = acc[5] + b1.y; v1.z = acc[6] + b1.z; v1.w = acc[7] + b1.w;
        float* xo = xi + (size_t)widx * 64 + c0;
        if (residual) {
            const float4 p0 = *(const float4*)xo;
            const float4 p1 = *(const float4*)(xo + 4);
            v0.x += p0.x; v0.y += p0.y; v0.z += p0.z; v0.w += p0.w;
            v1.x += p1.x; v1.y += p1.y; v1.z += p1.z; v1.w += p1.w;
        }
        v0.x = eluf(v0.x); v0.y = eluf(v0.y); v0.z = eluf(v0.z); v0.w = eluf(v0.w);
        v1.x = eluf(v1.x); v1.y = eluf(v1.y); v1.z = eluf(v1.z); v1.w = eluf(v1.w);
        *(float4*)xo = v0;
        *(float4*)(xo + 4) = v1;
    }
}

// ---------------- kernel: LN + 2-layer MLP on the 50 target nodes ----------------
__global__ void readout_kernel(const float* __restrict__ xi, const int* __restrict__ batch,
                               const float* __restrict__ ln_g, const float* __restrict__ ln_b,
                               const float* __restrict__ l1w, const float* __restrict__ l1b,
                               const float* __restrict__ l2w, const float* __restrict__ l2b,
                               float* __restrict__ out) {
    int b = blockIdx.x;
    int t = threadIdx.x;   // 64 threads, one wave
    __shared__ int tg_s;
    if (t == 0) {
        int lo = 0, hi = NN;
        while (lo < hi) {
            int mid = (lo + hi) >> 1;
            if (batch[mid] < b) lo = mid + 1; else hi = mid;
        }
        tg_s = lo;
    }
    __syncthreads();
    int tg = tg_s;
    float x = xi[(size_t)tg * 64 + t];
    float s = x;
    #pragma unroll
    for (int mask = 1; mask <= 32; mask <<= 1) s += __shfl_xor(s, mask);
    float mu = s * (1.f / 64.f);
    float d = x - mu;
    float v = d * d;
    #pragma unroll
    for (int mask = 1; mask <= 32; mask <<= 1) v += __shfl_xor(v, mask);
    float var = v * (1.f / 64.f);
    float xn = d * rsqrtf(var + 1e-5f) * ln_g[t] + ln_b[t];
    __shared__ float sx[64];
    sx[t] = xn;
    __syncthreads();
    float acc = l1b[t];
    for (int k = 0; k < 64; ++k) acc += sx[k] * l1w[k * 64 + t];
    acc = eluf(acc);
    __shared__ float st[64];
    st[t] = acc;
    __syncthreads();
    if (t < 3) {
        float o = l2b[t];
        for (int k = 0; k < 64; ++k) o += st[k] * l2w[k * 3 + t];
        out[b * 3 + t] = o;
    }
}

extern "C" void kernel_launch(void* const* d_in, const int* in_sizes, int n_in,
                              void* d_out, int out_size, void* d_ws, size_t ws_size,
                              hipStream_t stream) {
    const float* x        = (const float*)d_in[0];
    const int*   ei       = (const int*)d_in[1];
    const float* ea       = (const float*)d_in[2];
    const int*   batch    = (const int*)d_in[3];
    const float* ee_w1    = (const float*)d_in[4];
    const float* ee_b1    = (const float*)d_in[5];
    const float* ee_w2    = (const float*)d_in[6];
    const float* ee_b2    = (const float*)d_in[7];
    const float* W1       = (const float*)d_in[8];
    const float* Ws       = (const float*)d_in[9];
    const float* att_src  = (const float*)d_in[10];
    const float* att_dst  = (const float*)d_in[11];
    const float* We       = (const float*)d_in[12];
    const float* att_e    = (const float*)d_in[13];
    const float* bias     = (const float*)d_in[14];
    const float* ln_g     = (const float*)d_in[15];
    const float* ln_b     = (const float*)d_in[16];
    const float* lin1_w   = (const float*)d_in[17];
    const float* lin1_b   = (const float*)d_in[18];
    const float* lin2_w   = (const float*)d_in[19];
    const float* lin2_b   = (const float*)d_in[20];
    float* out = (float*)d_out;

    // ---- workspace carve-up (256B aligned) ----
    char* ws = (char*)d_ws;
    size_t off = 0;
    auto alloc = [&](size_t bytes) -> char* {
        char* p = ws + off;
        off += (bytes + 255) & ~(size_t)255;
        return p;
    };
    float* ew      = (float*)alloc((size_t)ET * 4);
    float* ce      = (float*)alloc(12 * 4);
    unsigned short* hbuf = (unsigned short*)alloc((size_t)NN * 256 * 2);
    float* asrc    = (float*)alloc((size_t)NN * 4 * 4);
    float* adst    = (float*)alloc((size_t)NN * 4 * 4);
    float* xi      = (float*)alloc((size_t)NN * 64 * 4);
    int*   deg     = (int*)alloc(((size_t)NN * 2 + 64) * 4); // deg | fill | ew_sum
    int*   fill    = deg + NN;
    float* ew_sum  = (float*)(deg + 2 * NN);
    int*   row_ptr = (int*)alloc((size_t)(NN + 1) * 4);
    int*   bsum    = (int*)alloc(64 * 4);
    int2*  csr     = (int2*)alloc((size_t)ET * 8);
    (void)ws_size; (void)n_in; (void)in_sizes; (void)out_size;

    const int* ei_src = ei;
    const int* ei_dst = ei + NE;

    // 1. edge encoder + dst histogram (fused); single memset covers deg+fill+ew_sum
    hipMemsetAsync(deg, 0, ((size_t)NN * 2 + 64) * 4, stream);
    edge_mlp_kernel<<<(ET + 255) / 256, 256, 0, stream>>>(ea, ee_w1, ee_b1, ee_w2, ee_b2,
                                                          ei_dst, deg, ew, ew_sum);

    // 2. CSR by dst (multi-block scan; phase A also does self-loop ew fill + ce)
    scan_blocks<<<NBLK, SCAN_B, 0, stream>>>(deg, row_ptr, bsum, We, att_e, ew_sum, ew, ce);
    scan_fixup<<<(NN + 255) / 256, 256, 0, stream>>>(bsum, row_ptr);
    scatter_kernel<<<(ET + 255) / 256, 256, 0, stream>>>(ei_src, ei_dst, row_ptr, ew, fill, csr);

    // 3. three GAT layers
    const int ntBlocks = (NN + 7) / 8;
    const int agBlocks = (NN + 3) / 4;
    // layer 0
    node_transform<16><<<ntBlocks, 256, 0, stream>>>(x, W1, att_src + 0 * 256, att_dst + 0 * 256,
                                                     hbuf, asrc, adst);
    gat_aggregate<<<agBlocks, 256, 0, stream>>>(hbuf, asrc, adst, csr, ce + 0 * 4,
                                                bias + 0 * 64, row_ptr, xi, 0);
    // layers 1..2 (residual)
    for (int l = 0; l < 2; ++l) {
        node_transform<64><<<ntBlocks, 256, 0, stream>>>(xi, Ws + (size_t)l * 64 * 256,
                                                         att_src + (l + 1) * 256,
                                                         att_dst + (l + 1) * 256,
                                                         hbuf, asrc, adst);
        gat_aggregate<<<agBlocks, 256, 0, stream>>>(hbuf, asrc, adst, csr, ce + (l + 1) * 4,
                                                    bias + (l + 1) * 64, row_ptr, xi, 1);
    }

    // 4. readout
    readout_kernel<<<NB, 64, 0, stream>>>(xi, batch, ln_g, ln_b, lin1_w, lin1_b, lin2_w, lin2_b, out);
}

// Round 12
// 539.981 us; speedup vs baseline: 4.9787x; 1.1084x over previous
//
#include <hip/hip_runtime.h>
#include <cstddef>
#include <cstdint>

constexpr int NN = 50000;          // nodes
constexpr int NE = 800000;         // edges (no self loops)
constexpr int ET = NE + NN;        // edges + self loops
constexpr int NB = 50;             // graphs
constexpr int SCAN_B = 1024;
constexpr int NBLK = (NN + SCAN_B - 1) / SCAN_B;   // 49

__device__ __forceinline__ float eluf(float x) { return x > 0.f ? x : expm1f(x); }

// round-to-nearest-even fp32 -> bf16 (as ushort)
__device__ __forceinline__ unsigned short f2bf(float f) {
    unsigned int u = __float_as_uint(f);
    unsigned int r = (u + 0x7fffu + ((u >> 16) & 1u)) >> 16;
    return (unsigned short)r;
}

// ---------------- kernel: edge encoder MLP + sum(ew) + dst histogram ----------------
__global__ void edge_mlp_kernel(const float* __restrict__ ea,
                                const float* __restrict__ w1, const float* __restrict__ b1,
                                const float* __restrict__ w2, const float* __restrict__ b2,
                                const int* __restrict__ ei_dst, int* __restrict__ deg,
                                float* __restrict__ ew, float* __restrict__ ew_sum) {
    // weights transposed+interleaved: wt[j*8 + {0..4}]=w1[i][j], [5]=b1[j], [6]=w2[j]
    __shared__ float wt[64 * 8];
    int t = threadIdx.x;
    if (t < 64) {
        #pragma unroll
        for (int i = 0; i < 5; ++i) wt[t * 8 + i] = w1[i * 64 + t];
        wt[t * 8 + 5] = b1[t];
        wt[t * 8 + 6] = w2[t];
        wt[t * 8 + 7] = 0.f;
    }
    __syncthreads();
    int e = blockIdx.x * 256 + t;
    float val = 0.f;
    if (e < NE) {
        float a0 = ea[e*5+0], a1 = ea[e*5+1], a2 = ea[e*5+2], a3 = ea[e*5+3], a4 = ea[e*5+4];
        float acc = b2[0];
        #pragma unroll 8
        for (int j = 0; j < 64; ++j) {
            const float4 lo = *(const float4*)&wt[j * 8];
            const float4 hi = *(const float4*)&wt[j * 8 + 4];
            float hj = hi.y + a0*lo.x + a1*lo.y + a2*lo.z + a3*lo.w + a4*hi.x;
            acc += fmaxf(hj, 0.f) * hi.z;
        }
        val = 1.f / (1.f + __expf(-acc));
        ew[e] = val;
    }
    if (e < ET) {
        int d = (e < NE) ? ei_dst[e] : (e - NE);
        atomicAdd(&deg[d], 1);
    }
    __shared__ float red[256];
    red[t] = val;
    __syncthreads();
    for (int off = 128; off > 0; off >>= 1) {
        if (t < off) red[t] += red[t + off];
        __syncthreads();
    }
    if (t == 0) atomicAdd(ew_sum, red[0]);
}

// ---------------- scan phase A (+ fused prep: self-loop ew fill, ce[l][h]) ----------------
__global__ void scan_blocks(const int* __restrict__ deg, int* __restrict__ row_ptr,
                            int* __restrict__ bsum,
                            const float* __restrict__ We, const float* __restrict__ att_e,
                            const float* __restrict__ ew_sum, float* __restrict__ ew,
                            float* __restrict__ ce) {
    __shared__ int sdata[SCAN_B];
    int t = threadIdx.x;
    int i = blockIdx.x * SCAN_B + t;
    // fused prep work (independent of the scan)
    if (i < NN) ew[NE + i] = ew_sum[0] * (1.f / (float)NE);
    if (i < 12) {
        int l = i >> 2, h = i & 3;
        float s = 0.f;
        for (int c = 0; c < 64; ++c)
            s += We[l*256 + h*64 + c] * att_e[l*256 + h*64 + c];
        ce[i] = s;
    }
    int v = (i < NN) ? deg[i] : 0;
    sdata[t] = v;
    __syncthreads();
    for (int off = 1; off < SCAN_B; off <<= 1) {
        int tv = (t >= off) ? sdata[t - off] : 0;
        __syncthreads();
        sdata[t] += tv;
        __syncthreads();
    }
    if (i < NN) row_ptr[i + 1] = sdata[t];
    if (t == SCAN_B - 1) bsum[blockIdx.x] = sdata[t];
}

// scan phase B+C fused: each block wave-scans the 49 block sums in-LDS, then
// adds the offset to its range of row_ptr.
__global__ void scan_fixup(const int* __restrict__ bsum, int* __restrict__ row_ptr) {
    __shared__ int sboff[64];
    int t = threadIdx.x;   // 256
    if (t < 64) {
        int v = (t < NBLK) ? bsum[t] : 0;
        int inc = v;
        #pragma unroll
        for (int off = 1; off < 64; off <<= 1) {
            int n = __shfl_up(inc, off);
            if (t >= off) inc += n;
        }
        sboff[t] = inc - v;   // exclusive scan
    }
    __syncthreads();
    int i = blockIdx.x * 256 + t;
    if (i < NN) row_ptr[i + 1] += sboff[i >> 10];
    if (i == 0) row_ptr[0] = 0;
}

// write per-slot {src, ew} as one int2 so the aggregate does a single 8-B load
__global__ void scatter_kernel(const int* __restrict__ ei_src, const int* __restrict__ ei_dst,
                               const int* __restrict__ row_ptr, const float* __restrict__ ew,
                               int* __restrict__ fill, int2* __restrict__ csr) {
    int e = blockIdx.x * 256 + threadIdx.x;
    if (e >= ET) return;
    int d = (e < NE) ? ei_dst[e] : (e - NE);
    int s = (e < NE) ? ei_src[e] : (e - NE);
    int pos = atomicAdd(&fill[d], 1);
    csr[row_ptr[d] + pos] = make_int2(s, __float_as_int(ew[e]));
}

// ---------------- kernel: h = xin @ W (bf16 via LDS bounce), fused alphas ----------------
// x is read at BLOCK-UNIFORM addresses directly from global (scalar-load path:
// s_load + v_fma with SGPR operand) — no LDS staging for x, no vector LDS reads
// (those spill: R8/R10). hs bounce store kept (R7-proven, fixes write amplification).
template <int FIN>
__global__ void node_transform(const float* __restrict__ xin, const float* __restrict__ W,
                               const float* __restrict__ a_s, const float* __restrict__ a_d,
                               unsigned short* __restrict__ hb, float* __restrict__ asrc,
                               float* __restrict__ adst) {
    const int t = threadIdx.x;
    const int n0 = blockIdx.x * 8;   // NN % 8 == 0 -> rows always in-bounds
    __shared__ unsigned short hs[8 * 256];   // 4 KB staging for wide stores
    float acc[8];
    #pragma unroll
    for (int i = 0; i < 8; ++i) acc[i] = 0.f;
    for (int k = 0; k < FIN; ++k) {
        float wv = W[k * 256 + t];
        #pragma unroll
        for (int i = 0; i < 8; ++i)
            acc[i] += xin[(size_t)(n0 + i) * FIN + k] * wv;   // uniform address
    }
    float as_t = a_s[t], ad_t = a_d[t];
    int lane = t & 63, head = t >> 6;
    #pragma unroll
    for (int i = 0; i < 8; ++i) {
        hs[i * 256 + t] = f2bf(acc[i]);
        float vs = acc[i] * as_t, vd = acc[i] * ad_t;
        #pragma unroll
        for (int mask = 1; mask <= 32; mask <<= 1) {
            vs += __shfl_xor(vs, mask);
            vd += __shfl_xor(vd, mask);
        }
        if (lane == 0) {
            asrc[(n0 + i) * 4 + head] = vs;
            adst[(n0 + i) * 4 + head] = vd;
        }
    }
    __syncthreads();
    // 256 threads x 16 B = 4096 B = the block's 8 rows of 512 B, fully coalesced
    ((uint4*)(hb + (size_t)n0 * 256))[t] = ((const uint4*)hs)[t];
}

// ---------------- kernel: per-dst-node softmax-free aggregation ----------------
// EXACT R9 config: one wave per node, two halves, 2-deep gather pipeline,
// no launch_bounds (4-deep + launch_bounds regressed: R11, 71.3 -> 74.9 us).
__global__ void gat_aggregate(const unsigned short* __restrict__ hb,
                              const float* __restrict__ asrc, const float* __restrict__ adst,
                              const int2* __restrict__ csr, const float* __restrict__ ce_l,
                              const float* __restrict__ bias_l,
                              const int* __restrict__ row_ptr,
                              float* __restrict__ xi, int residual) {
    int widx = (blockIdx.x * 256 + threadIdx.x) >> 6;   // node
    if (widx >= NN) return;
    int lane = threadIdx.x & 63;
    int half = lane >> 5;
    int li = lane & 31;        // channels li*8 .. li*8+7
    int head = li >> 3;        // head
    int start = row_ptr[widx], end = row_ptr[widx + 1];
    float adw = adst[widx * 4 + head];
    float ceh = ce_l[head];
    const uint4* hbv = (const uint4*)hb;

    float acc[8];
    #pragma unroll
    for (int r = 0; r < 8; ++r) acc[r] = 0.f;
    float psum = 0.f;

    #define PROC(EI)                                                                  \
        {                                                                             \
            const int2 se = csr[EI];                                                  \
            int s = se.x;                                                             \
            float w = __int_as_float(se.y);                                           \
            const uint4 q = hbv[(unsigned)s * 32u + (unsigned)li];                    \
            float v = asrc[s * 4 + head] + adw + w * ceh;                             \
            v = v > 0.f ? v : 0.2f * v;                                               \
            float p = __expf(v);                                                      \
            psum += p;                                                                \
            acc[0] += p * __uint_as_float(q.x << 16);                                 \
            acc[1] += p * __uint_as_float(q.x & 0xffff0000u);                         \
            acc[2] += p * __uint_as_float(q.y << 16);                                 \
            acc[3] += p * __uint_as_float(q.y & 0xffff0000u);                         \
            acc[4] += p * __uint_as_float(q.z << 16);                                 \
            acc[5] += p * __uint_as_float(q.z & 0xffff0000u);                         \
            acc[6] += p * __uint_as_float(q.w << 16);                                 \
            acc[7] += p * __uint_as_float(q.w & 0xffff0000u);                         \
        }

    int ei = start + half;
    for (; ei + 2 < end; ei += 4) {   // 2 edges per half per iter -> 2 gathers in flight
        PROC(ei);
        PROC(ei + 2);
    }
    if (ei < end) PROC(ei);
    #undef PROC

    // combine the two halves (same channels, disjoint edge sets)
    psum += __shfl_xor(psum, 32);
    #pragma unroll
    for (int r = 0; r < 8; ++r) acc[r] += __shfl_xor(acc[r], 32);

    float inv = 1.f / (psum + 1e-16f);
    #pragma unroll
    for (int r = 0; r < 8; ++r) acc[r] *= inv;

    // head mean: lanes li, li^8, li^16, li^24 hold same channel-in-head, different heads
    #pragma unroll
    for (int r = 0; r < 8; ++r) {
        acc[r] += __shfl_xor(acc[r], 8);
        acc[r] += __shfl_xor(acc[r], 16);
        acc[r] *= 0.25f;
    }

    if (lane < 8) {
        int c0 = lane * 8;
        const float4 b0 = *(const float4*)(bias_l + c0);
        const float4 b1 = *(const float4*)(bias_l + c0 + 4);
        float4 v0, v1;
        v0.x = acc[0] + b0.x; v0.y = acc[1] + b0.y; v0.z = acc[2] + b0.z; v0.w = acc[3] + b0.w;
        v1.x = acc[4] + b1.x; v1.y = acc[5] + b1.y; v1.z = acc[6] + b1.z; v1.w = acc[7] + b1.w;
        float* xo = xi + (size_t)widx * 64 + c0;
        if (residual) {
            const float4 p0 = *(const float4*)xo;
            const float4 p1 = *(const float4*)(xo + 4);
            v0.x += p0.x; v0.y += p0.y; v0.z += p0.z; v0.w += p0.w;
            v1.x += p1.x; v1.y += p1.y; v1.z += p1.z; v1.w += p1.w;
        }
        v0.x = eluf(v0.x); v0.y = eluf(v0.y); v0.z = eluf(v0.z); v0.w = eluf(v0.w);
        v1.x = eluf(v1.x); v1.y = eluf(v1.y); v1.z = eluf(v1.z); v1.w = eluf(v1.w);
        *(float4*)xo = v0;
        *(float4*)(xo + 4) = v1;
    }
}

// ---------------- kernel: LN + 2-layer MLP on the 50 target nodes ----------------
__global__ void readout_kernel(const float* __restrict__ xi, const int* __restrict__ batch,
                               const float* __restrict__ ln_g, const float* __restrict__ ln_b,
                               const float* __restrict__ l1w, const float* __restrict__ l1b,
                               const float* __restrict__ l2w, const float* __restrict__ l2b,
                               float* __restrict__ out) {
    int b = blockIdx.x;
    int t = threadIdx.x;   // 64 threads, one wave
    __shared__ int tg_s;
    if (t == 0) {
        int lo = 0, hi = NN;
        while (lo < hi) {
            int mid = (lo + hi) >> 1;
            if (batch[mid] < b) lo = mid + 1; else hi = mid;
        }
        tg_s = lo;
    }
    __syncthreads();
    int tg = tg_s;
    float x = xi[(size_t)tg * 64 + t];
    float s = x;
    #pragma unroll
    for (int mask = 1; mask <= 32; mask <<= 1) s += __shfl_xor(s, mask);
    float mu = s * (1.f / 64.f);
    float d = x - mu;
    float v = d * d;
    #pragma unroll
    for (int mask = 1; mask <= 32; mask <<= 1) v += __shfl_xor(v, mask);
    float var = v * (1.f / 64.f);
    float xn = d * rsqrtf(var + 1e-5f) * ln_g[t] + ln_b[t];
    __shared__ float sx[64];
    sx[t] = xn;
    __syncthreads();
    float acc = l1b[t];
    for (int k = 0; k < 64; ++k) acc += sx[k] * l1w[k * 64 + t];
    acc = eluf(acc);
    __shared__ float st[64];
    st[t] = acc;
    __syncthreads();
    if (t < 3) {
        float o = l2b[t];
        for (int k = 0; k < 64; ++k) o += st[k] * l2w[k * 3 + t];
        out[b * 3 + t] = o;
    }
}

extern "C" void kernel_launch(void* const* d_in, const int* in_sizes, int n_in,
                              void* d_out, int out_size, void* d_ws, size_t ws_size,
                              hipStream_t stream) {
    const float* x        = (const float*)d_in[0];
    const int*   ei       = (const int*)d_in[1];
    const float* ea       = (const float*)d_in[2];
    const int*   batch    = (const int*)d_in[3];
    const float* ee_w1    = (const float*)d_in[4];
    const float* ee_b1    = (const float*)d_in[5];
    const float* ee_w2    = (const float*)d_in[6];
    const float* ee_b2    = (const float*)d_in[7];
    const float* W1       = (const float*)d_in[8];
    const float* Ws       = (const float*)d_in[9];
    const float* att_src  = (const float*)d_in[10];
    const float* att_dst  = (const float*)d_in[11];
    const float* We       = (const float*)d_in[12];
    const float* att_e    = (const float*)d_in[13];
    const float* bias     = (const float*)d_in[14];
    const float* ln_g     = (const float*)d_in[15];
    const float* ln_b     = (const float*)d_in[16];
    const float* lin1_w   = (const float*)d_in[17];
    const float* lin1_b   = (const float*)d_in[18];
    const float* lin2_w   = (const float*)d_in[19];
    const float* lin2_b   = (const float*)d_in[20];
    float* out = (float*)d_out;

    // ---- workspace carve-up (256B aligned) ----
    char* ws = (char*)d_ws;
    size_t off = 0;
    auto alloc = [&](size_t bytes) -> char* {
        char* p = ws + off;
        off += (bytes + 255) & ~(size_t)255;
        return p;
    };
    float* ew      = (float*)alloc((size_t)ET * 4);
    float* ce      = (float*)alloc(12 * 4);
    unsigned short* hbuf = (unsigned short*)alloc((size_t)NN * 256 * 2);
    float* asrc    = (float*)alloc((size_t)NN * 4 * 4);
    float* adst    = (float*)alloc((size_t)NN * 4 * 4);
    float* xi      = (float*)alloc((size_t)NN * 64 * 4);
    int*   deg     = (int*)alloc(((size_t)NN * 2 + 64) * 4); // deg | fill | ew_sum
    int*   fill    = deg + NN;
    float* ew_sum  = (float*)(deg + 2 * NN);
    int*   row_ptr = (int*)alloc((size_t)(NN + 1) * 4);
    int*   bsum    = (int*)alloc(64 * 4);
    int2*  csr     = (int2*)alloc((size_t)ET * 8);
    (void)ws_size; (void)n_in; (void)in_sizes; (void)out_size;

    const int* ei_src = ei;
    const int* ei_dst = ei + NE;

    // 1. edge encoder + dst histogram (fused); single memset covers deg+fill+ew_sum
    hipMemsetAsync(deg, 0, ((size_t)NN * 2 + 64) * 4, stream);
    edge_mlp_kernel<<<(ET + 255) / 256, 256, 0, stream>>>(ea, ee_w1, ee_b1, ee_w2, ee_b2,
                                                          ei_dst, deg, ew, ew_sum);

    // 2. CSR by dst (multi-block scan; phase A also does self-loop ew fill + ce)
    scan_blocks<<<NBLK, SCAN_B, 0, stream>>>(deg, row_ptr, bsum, We, att_e, ew_sum, ew, ce);
    scan_fixup<<<(NN + 255) / 256, 256, 0, stream>>>(bsum, row_ptr);
    scatter_kernel<<<(ET + 255) / 256, 256, 0, stream>>>(ei_src, ei_dst, row_ptr, ew, fill, csr);

    // 3. three GAT layers
    const int ntBlocks = (NN + 7) / 8;
    const int agBlocks = (NN + 3) / 4;
    // layer 0
    node_transform<16><<<ntBlocks, 256, 0, stream>>>(x, W1, att_src + 0 * 256, att_dst + 0 * 256,
                                                     hbuf, asrc, adst);
    gat_aggregate<<<agBlocks, 256, 0, stream>>>(hbuf, asrc, adst, csr, ce + 0 * 4,
                                                bias + 0 * 64, row_ptr, xi, 0);
    // layers 1..2 (residual)
    for (int l = 0; l < 2; ++l) {
        node_transform<64><<<ntBlocks, 256, 0, stream>>>(xi, Ws + (size_t)l * 64 * 256,
                                                         att_src + (l + 1) * 256,
                                                         att_dst + (l + 1) * 256,
                                                         hbuf, asrc, adst);
        gat_aggregate<<<agBlocks, 256, 0, stream>>>(hbuf, asrc, adst, csr, ce + (l + 1) * 4,
                                                    bias + (l + 1) * 64, row_ptr, xi, 1);
    }

    // 4. readout
    readout_kernel<<<NB, 64, 0, stream>>>(xi, batch, ln_g, ln_b, lin1_w, lin1_b, lin2_w, lin2_b, out);
}

// Round 13
// 539.230 us; speedup vs baseline: 4.9856x; 1.0014x over previous
//
#include <hip/hip_runtime.h>
#include <cstddef>
#include <cstdint>

constexpr int NN = 50000;          // nodes
constexpr int NE = 800000;         // edges (no self loops)
constexpr int ET = NE + NN;        // edges + self loops
constexpr int NB = 50;             // graphs
constexpr int SCAN_B = 1024;
constexpr int NBLK = (NN + SCAN_B - 1) / SCAN_B;   // 49
constexpr int NTB  = NN / 8;                       // node_transform blocks (6250)
constexpr int MLPB = (ET + 255) / 256;             // edge-mlp blocks

typedef float v2f __attribute__((ext_vector_type(2)));

__device__ __forceinline__ float eluf(float x) { return x > 0.f ? x : expm1f(x); }

// round-to-nearest-even fp32 -> bf16 (as ushort)
__device__ __forceinline__ unsigned short f2bf(float f) {
    unsigned int u = __float_as_uint(f);
    unsigned int r = (u + 0x7fffu + ((u >> 16) & 1u)) >> 16;
    return (unsigned short)r;
}

// ---------------- front kernel: node_transform<16> (blocks [0,NTB)) fused with
// edge-MLP + sum(ew) + dst histogram (blocks [NTB, NTB+MLPB)) — independent work
// co-executing in one dispatch. Branch is block-uniform.
__global__ void front_kernel(const float* __restrict__ xin, const float* __restrict__ W,
                             const float* __restrict__ a_s, const float* __restrict__ a_d,
                             unsigned short* __restrict__ hb, float* __restrict__ asrc,
                             float* __restrict__ adst,
                             const float* __restrict__ ea,
                             const float* __restrict__ w1, const float* __restrict__ b1,
                             const float* __restrict__ w2, const float* __restrict__ b2,
                             const int* __restrict__ ei_dst, int* __restrict__ deg,
                             float* __restrict__ ew, float* __restrict__ ew_sum) {
    __shared__ float wt[64 * 8];
    __shared__ float red[256];
    __shared__ unsigned short hs[8 * 256];
    const int t = threadIdx.x;
    if (blockIdx.x < NTB) {
        // ----- node_transform, FIN=16, scalar/uniform x loads (R12-proven) -----
        const int FIN = 16;
        const int n0 = blockIdx.x * 8;
        float acc[8];
        #pragma unroll
        for (int i = 0; i < 8; ++i) acc[i] = 0.f;
        for (int k = 0; k < FIN; ++k) {
            float wv = W[k * 256 + t];
            #pragma unroll
            for (int i = 0; i < 8; ++i)
                acc[i] += xin[(size_t)(n0 + i) * FIN + k] * wv;   // uniform address
        }
        float as_t = a_s[t], ad_t = a_d[t];
        int lane = t & 63, head = t >> 6;
        #pragma unroll
        for (int i = 0; i < 8; ++i) {
            hs[i * 256 + t] = f2bf(acc[i]);
            float vs = acc[i] * as_t, vd = acc[i] * ad_t;
            #pragma unroll
            for (int mask = 1; mask <= 32; mask <<= 1) {
                vs += __shfl_xor(vs, mask);
                vd += __shfl_xor(vd, mask);
            }
            if (lane == 0) {
                asrc[(n0 + i) * 4 + head] = vs;
                adst[(n0 + i) * 4 + head] = vd;
            }
        }
        __syncthreads();
        ((uint4*)(hb + (size_t)n0 * 256))[t] = ((const uint4*)hs)[t];
    } else {
        // ----- edge-MLP + histogram (R9-proven body) -----
        if (t < 64) {
            #pragma unroll
            for (int i = 0; i < 5; ++i) wt[t * 8 + i] = w1[i * 64 + t];
            wt[t * 8 + 5] = b1[t];
            wt[t * 8 + 6] = w2[t];
            wt[t * 8 + 7] = 0.f;
        }
        __syncthreads();
        int e = (blockIdx.x - NTB) * 256 + t;
        float val = 0.f;
        if (e < NE) {
            float a0 = ea[e*5+0], a1 = ea[e*5+1], a2 = ea[e*5+2], a3 = ea[e*5+3], a4 = ea[e*5+4];
            float acc = b2[0];
            #pragma unroll 8
            for (int j = 0; j < 64; ++j) {
                const float4 lo = *(const float4*)&wt[j * 8];
                const float4 hi = *(const float4*)&wt[j * 8 + 4];
                float hj = hi.y + a0*lo.x + a1*lo.y + a2*lo.z + a3*lo.w + a4*hi.x;
                acc += fmaxf(hj, 0.f) * hi.z;
            }
            val = 1.f / (1.f + __expf(-acc));
            ew[e] = val;
        }
        if (e < ET) {
            int d = (e < NE) ? ei_dst[e] : (e - NE);
            atomicAdd(&deg[d], 1);
        }
        red[t] = val;
        __syncthreads();
        for (int off = 128; off > 0; off >>= 1) {
            if (t < off) red[t] += red[t + off];
            __syncthreads();
        }
        if (t == 0) atomicAdd(ew_sum, red[0]);
    }
}

// ---------------- scan phase A (+ fused prep: self-loop ew fill, ce[l][h]) ----------------
__global__ void scan_blocks(const int* __restrict__ deg, int* __restrict__ row_ptr,
                            int* __restrict__ bsum,
                            const float* __restrict__ We, const float* __restrict__ att_e,
                            const float* __restrict__ ew_sum, float* __restrict__ ew,
                            float* __restrict__ ce) {
    __shared__ int sdata[SCAN_B];
    int t = threadIdx.x;
    int i = blockIdx.x * SCAN_B + t;
    // fused prep work (independent of the scan)
    if (i < NN) ew[NE + i] = ew_sum[0] * (1.f / (float)NE);
    if (i < 12) {
        int l = i >> 2, h = i & 3;
        float s = 0.f;
        for (int c = 0; c < 64; ++c)
            s += We[l*256 + h*64 + c] * att_e[l*256 + h*64 + c];
        ce[i] = s;
    }
    int v = (i < NN) ? deg[i] : 0;
    sdata[t] = v;
    __syncthreads();
    for (int off = 1; off < SCAN_B; off <<= 1) {
        int tv = (t >= off) ? sdata[t - off] : 0;
        __syncthreads();
        sdata[t] += tv;
        __syncthreads();
    }
    if (i < NN) row_ptr[i + 1] = sdata[t];
    if (t == SCAN_B - 1) bsum[blockIdx.x] = sdata[t];
}

// scan phase B+C fused: each block wave-scans the 49 block sums in-LDS, then
// adds the offset to its range of row_ptr.
__global__ void scan_fixup(const int* __restrict__ bsum, int* __restrict__ row_ptr) {
    __shared__ int sboff[64];
    int t = threadIdx.x;   // 256
    if (t < 64) {
        int v = (t < NBLK) ? bsum[t] : 0;
        int inc = v;
        #pragma unroll
        for (int off = 1; off < 64; off <<= 1) {
            int n = __shfl_up(inc, off);
            if (t >= off) inc += n;
        }
        sboff[t] = inc - v;   // exclusive scan
    }
    __syncthreads();
    int i = blockIdx.x * 256 + t;
    if (i < NN) row_ptr[i + 1] += sboff[i >> 10];
    if (i == 0) row_ptr[0] = 0;
}

// write per-slot {src, ew} as one int2 so the aggregate does a single 8-B load
__global__ void scatter_kernel(const int* __restrict__ ei_src, const int* __restrict__ ei_dst,
                               const int* __restrict__ row_ptr, const float* __restrict__ ew,
                               int* __restrict__ fill, int2* __restrict__ csr) {
    int e = blockIdx.x * 256 + threadIdx.x;
    if (e >= ET) return;
    int d = (e < NE) ? ei_dst[e] : (e - NE);
    int s = (e < NE) ? ei_src[e] : (e - NE);
    int pos = atomicAdd(&fill[d], 1);
    csr[row_ptr[d] + pos] = make_int2(s, __float_as_int(ew[e]));
}

// ---------------- kernel: h = xi @ W (bf16 via LDS bounce), fused alphas (layers 1-2) ----
// Scalar/uniform x loads; vector LDS reads spill (R8/R10) — do not vectorize.
__global__ void node_transform64(const float* __restrict__ xin, const float* __restrict__ W,
                                 const float* __restrict__ a_s, const float* __restrict__ a_d,
                                 unsigned short* __restrict__ hb, float* __restrict__ asrc,
                                 float* __restrict__ adst) {
    const int FIN = 64;
    const int t = threadIdx.x;
    const int n0 = blockIdx.x * 8;
    __shared__ unsigned short hs[8 * 256];
    float acc[8];
    #pragma unroll
    for (int i = 0; i < 8; ++i) acc[i] = 0.f;
    for (int k = 0; k < FIN; ++k) {
        float wv = W[k * 256 + t];
        #pragma unroll
        for (int i = 0; i < 8; ++i)
            acc[i] += xin[(size_t)(n0 + i) * FIN + k] * wv;   // uniform address
    }
    float as_t = a_s[t], ad_t = a_d[t];
    int lane = t & 63, head = t >> 6;
    #pragma unroll
    for (int i = 0; i < 8; ++i) {
        hs[i * 256 + t] = f2bf(acc[i]);
        float vs = acc[i] * as_t, vd = acc[i] * ad_t;
        #pragma unroll
        for (int mask = 1; mask <= 32; mask <<= 1) {
            vs += __shfl_xor(vs, mask);
            vd += __shfl_xor(vd, mask);
        }
        if (lane == 0) {
            asrc[(n0 + i) * 4 + head] = vs;
            adst[(n0 + i) * 4 + head] = vd;
        }
    }
    __syncthreads();
    ((uint4*)(hb + (size_t)n0 * 256))[t] = ((const uint4*)hs)[t];
}

// ---------------- kernel: per-dst-node softmax-free aggregation ----------------
// R9 2-deep two-half structure (proven optimal vs 4-deep: R11) with float2
// accumulators to form v_pk_fma_f32 (packed fp32 — identical fma rounding).
__global__ void gat_aggregate(const unsigned short* __restrict__ hb,
                              const float* __restrict__ asrc, const float* __restrict__ adst,
                              const int2* __restrict__ csr, const float* __restrict__ ce_l,
                              const float* __restrict__ bias_l,
                              const int* __restrict__ row_ptr,
                              float* __restrict__ xi, int residual) {
    int widx = (blockIdx.x * 256 + threadIdx.x) >> 6;   // node
    if (widx >= NN) return;
    int lane = threadIdx.x & 63;
    int half = lane >> 5;
    int li = lane & 31;        // channels li*8 .. li*8+7
    int head = li >> 3;        // head
    int start = row_ptr[widx], end = row_ptr[widx + 1];
    float adw = adst[widx * 4 + head];
    float ceh = ce_l[head];
    const uint4* hbv = (const uint4*)hb;

    v2f acc2[4];
    #pragma unroll
    for (int r = 0; r < 4; ++r) { acc2[r].x = 0.f; acc2[r].y = 0.f; }
    float psum = 0.f;

    #define PROC(EI)                                                                  \
        {                                                                             \
            const int2 se = csr[EI];                                                  \
            int s = se.x;                                                             \
            float w = __int_as_float(se.y);                                           \
            const uint4 q = hbv[(unsigned)s * 32u + (unsigned)li];                    \
            float v = asrc[s * 4 + head] + adw + w * ceh;                             \
            v = v > 0.f ? v : 0.2f * v;                                               \
            float p = __expf(v);                                                      \
            psum += p;                                                                \
            v2f pv; pv.x = p; pv.y = p;                                               \
            v2f h0; h0.x = __uint_as_float(q.x << 16); h0.y = __uint_as_float(q.x & 0xffff0000u); \
            v2f h1; h1.x = __uint_as_float(q.y << 16); h1.y = __uint_as_float(q.y & 0xffff0000u); \
            v2f h2; h2.x = __uint_as_float(q.z << 16); h2.y = __uint_as_float(q.z & 0xffff0000u); \
            v2f h3; h3.x = __uint_as_float(q.w << 16); h3.y = __uint_as_float(q.w & 0xffff0000u); \
            acc2[0] += pv * h0;                                                       \
            acc2[1] += pv * h1;                                                       \
            acc2[2] += pv * h2;                                                       \
            acc2[3] += pv * h3;                                                       \
        }

    int ei = start + half;
    for (; ei + 2 < end; ei += 4) {   // 2 edges per half per iter -> 2 gathers in flight
        PROC(ei);
        PROC(ei + 2);
    }
    if (ei < end) PROC(ei);
    #undef PROC

    float acc[8];
    acc[0] = acc2[0].x; acc[1] = acc2[0].y; acc[2] = acc2[1].x; acc[3] = acc2[1].y;
    acc[4] = acc2[2].x; acc[5] = acc2[2].y; acc[6] = acc2[3].x; acc[7] = acc2[3].y;

    // combine the two halves (same channels, disjoint edge sets)
    psum += __shfl_xor(psum, 32);
    #pragma unroll
    for (int r = 0; r < 8; ++r) acc[r] += __shfl_xor(acc[r], 32);

    float inv = 1.f / (psum + 1e-16f);
    #pragma unroll
    for (int r = 0; r < 8; ++r) acc[r] *= inv;

    // head mean: lanes li, li^8, li^16, li^24 hold same channel-in-head, different heads
    #pragma unroll
    for (int r = 0; r < 8; ++r) {
        acc[r] += __shfl_xor(acc[r], 8);
        acc[r] += __shfl_xor(acc[r], 16);
        acc[r] *= 0.25f;
    }

    if (lane < 8) {
        int c0 = lane * 8;
        const float4 b0 = *(const float4*)(bias_l + c0);
        const float4 b1 = *(const float4*)(bias_l + c0 + 4);
        float4 v0, v1;
        v0.x = acc[0] + b0.x; v0.y = acc[1] + b0.y; v0.z = acc[2] + b0.z; v0.w = acc[3] + b0.w;
        v1.x = acc[4] + b1.x; v1.y = acc[5] + b1.y; v1.z = acc[6] + b1.z; v1.w = acc[7] + b1.w;
        float* xo = xi + (size_t)widx * 64 + c0;
        if (residual) {
            const float4 p0 = *(const float4*)xo;
            const float4 p1 = *(const float4*)(xo + 4);
            v0.x += p0.x; v0.y += p0.y; v0.z += p0.z; v0.w += p0.w;
            v1.x += p1.x; v1.y += p1.y; v1.z += p1.z; v1.w += p1.w;
        }
        v0.x = eluf(v0.x); v0.y = eluf(v0.y); v0.z = eluf(v0.z); v0.w = eluf(v0.w);
        v1.x = eluf(v1.x); v1.y = eluf(v1.y); v1.z = eluf(v1.z); v1.w = eluf(v1.w);
        *(float4*)xo = v0;
        *(float4*)(xo + 4) = v1;
    }
}

// ---------------- kernel: LN + 2-layer MLP on the 50 target nodes ----------------
__global__ void readout_kernel(const float* __restrict__ xi, const int* __restrict__ batch,
                               const float* __restrict__ ln_g, const float* __restrict__ ln_b,
                               const float* __restrict__ l1w, const float* __restrict__ l1b,
                               const float* __restrict__ l2w, const float* __restrict__ l2b,
                               float* __restrict__ out) {
    int b = blockIdx.x;
    int t = threadIdx.x;   // 64 threads, one wave
    __shared__ int tg_s;
    if (t == 0) {
        int lo = 0, hi = NN;
        while (lo < hi) {
            int mid = (lo + hi) >> 1;
            if (batch[mid] < b) lo = mid + 1; else hi = mid;
        }
        tg_s = lo;
    }
    __syncthreads();
    int tg = tg_s;
    float x = xi[(size_t)tg * 64 + t];
    float s = x;
    #pragma unroll
    for (int mask = 1; mask <= 32; mask <<= 1) s += __shfl_xor(s, mask);
    float mu = s * (1.f / 64.f);
    float d = x - mu;
    float v = d * d;
    #pragma unroll
    for (int mask = 1; mask <= 32; mask <<= 1) v += __shfl_xor(v, mask);
    float var = v * (1.f / 64.f);
    float xn = d * rsqrtf(var + 1e-5f) * ln_g[t] + ln_b[t];
    __shared__ float sx[64];
    sx[t] = xn;
    __syncthreads();
    float acc = l1b[t];
    for (int k = 0; k < 64; ++k) acc += sx[k] * l1w[k * 64 + t];
    acc = eluf(acc);
    __shared__ float st[64];
    st[t] = acc;
    __syncthreads();
    if (t < 3) {
        float o = l2b[t];
        for (int k = 0; k < 64; ++k) o += st[k] * l2w[k * 3 + t];
        out[b * 3 + t] = o;
    }
}

extern "C" void kernel_launch(void* const* d_in, const int* in_sizes, int n_in,
                              void* d_out, int out_size, void* d_ws, size_t ws_size,
                              hipStream_t stream) {
    const float* x        = (const float*)d_in[0];
    const int*   ei       = (const int*)d_in[1];
    const float* ea       = (const float*)d_in[2];
    const int*   batch    = (const int*)d_in[3];
    const float* ee_w1    = (const float*)d_in[4];
    const float* ee_b1    = (const float*)d_in[5];
    const float* ee_w2    = (const float*)d_in[6];
    const float* ee_b2    = (const float*)d_in[7];
    const float* W1       = (const float*)d_in[8];
    const float* Ws       = (const float*)d_in[9];
    const float* att_src  = (const float*)d_in[10];
    const float* att_dst  = (const float*)d_in[11];
    const float* We       = (const float*)d_in[12];
    const float* att_e    = (const float*)d_in[13];
    const float* bias     = (const float*)d_in[14];
    const float* ln_g     = (const float*)d_in[15];
    const float* ln_b     = (const float*)d_in[16];
    const float* lin1_w   = (const float*)d_in[17];
    const float* lin1_b   = (const float*)d_in[18];
    const float* lin2_w   = (const float*)d_in[19];
    const float* lin2_b   = (const float*)d_in[20];
    float* out = (float*)d_out;

    // ---- workspace carve-up (256B aligned) ----
    char* ws = (char*)d_ws;
    size_t off = 0;
    auto alloc = [&](size_t bytes) -> char* {
        char* p = ws + off;
        off += (bytes + 255) & ~(size_t)255;
        return p;
    };
    float* ew      = (float*)alloc((size_t)ET * 4);
    float* ce      = (float*)alloc(12 * 4);
    unsigned short* hbuf = (unsigned short*)alloc((size_t)NN * 256 * 2);
    float* asrc    = (float*)alloc((size_t)NN * 4 * 4);
    float* adst    = (float*)alloc((size_t)NN * 4 * 4);
    float* xi      = (float*)alloc((size_t)NN * 64 * 4);
    int*   deg     = (int*)alloc(((size_t)NN * 2 + 64) * 4); // deg | fill | ew_sum
    int*   fill    = deg + NN;
    float* ew_sum  = (float*)(deg + 2 * NN);
    int*   row_ptr = (int*)alloc((size_t)(NN + 1) * 4);
    int*   bsum    = (int*)alloc(64 * 4);
    int2*  csr     = (int2*)alloc((size_t)ET * 8);
    (void)ws_size; (void)n_in; (void)in_sizes; (void)out_size;

    const int* ei_src = ei;
    const int* ei_dst = ei + NE;

    // 1. fused front: node_transform<16> (layer-0) + edge-MLP + histogram
    hipMemsetAsync(deg, 0, ((size_t)NN * 2 + 64) * 4, stream);
    front_kernel<<<NTB + MLPB, 256, 0, stream>>>(x, W1, att_src + 0 * 256, att_dst + 0 * 256,
                                                 hbuf, asrc, adst,
                                                 ea, ee_w1, ee_b1, ee_w2, ee_b2,
                                                 ei_dst, deg, ew, ew_sum);

    // 2. CSR by dst (multi-block scan; phase A also does self-loop ew fill + ce)
    scan_blocks<<<NBLK, SCAN_B, 0, stream>>>(deg, row_ptr, bsum, We, att_e, ew_sum, ew, ce);
    scan_fixup<<<(NN + 255) / 256, 256, 0, stream>>>(bsum, row_ptr);
    scatter_kernel<<<(ET + 255) / 256, 256, 0, stream>>>(ei_src, ei_dst, row_ptr, ew, fill, csr);

    // 3. three GAT layers (layer-0 transform already done in front_kernel)
    const int agBlocks = (NN + 3) / 4;
    gat_aggregate<<<agBlocks, 256, 0, stream>>>(hbuf, asrc, adst, csr, ce + 0 * 4,
                                                bias + 0 * 64, row_ptr, xi, 0);
    for (int l = 0; l < 2; ++l) {
        node_transform64<<<NTB, 256, 0, stream>>>(xi, Ws + (size_t)l * 64 * 256,
                                                  att_src + (l + 1) * 256,
                                                  att_dst + (l + 1) * 256,
                                                  hbuf, asrc, adst);
        gat_aggregate<<<agBlocks, 256, 0, stream>>>(hbuf, asrc, adst, csr, ce + (l + 1) * 4,
                                                    bias + (l + 1) * 64, row_ptr, xi, 1);
    }

    // 4. readout
    readout_kernel<<<NB, 64, 0, stream>>>(xi, batch, ln_g, ln_b, lin1_w, lin1_b, lin2_w, lin2_b, out);
}